// Round 8
// baseline (255.530 us; speedup 1.0000x reference)
//
#include <hip/hip_runtime.h>

// Parabolic morphological pooling: min-plus erosion then max-plus dilation,
// 7x7 parabola ||z||^2 * scale_c, 'same' padding. Register-streaming design.
//
// Round-8 change (single knob vs round 7): horizontal neighbor exchange via
// DPP wave_shr:1 / wave_shl:1 (v_mov_b32_dpp, pure VALU) instead of 6
// __shfl (ds_bpermute, DS pipe + lgkmcnt wait on the critical path).
// The DPP `old` operand injects the +-inf boundary into lane 0/63 for free,
// removing 12 cndmask + 2 cmp per pass as well.
//
//   - One wave owns a 256-wide row: lane l holds cols 4l..4l+3 (float4).
//   - Vertical passes: per-lane rolling 7-row register windows.
//   - Pipeline: X[gr] -> Hmin[gr] -> E[gr-3] -> Hmax[gr-3] -> out[gr-6].
//   - Outside image: +inf (erosion input), -inf (erosion output / dilation).
//   - ROWS=16 strips, rolled loop (I-cache safe), prefetch depth 2,
//     runtime wave-uniform warm-up guards.
// Expression tree identical to rounds 2/4/6/7 (all absmax 0.0).

#define ROWS 16
#define HH   256
#define WW   256
#define NTH  256

__device__ __forceinline__ float4 f4s(float v) { return float4{v, v, v, v}; }

__device__ __forceinline__ float4 f4min(float4 a, float4 b) {
    return float4{fminf(a.x,b.x), fminf(a.y,b.y), fminf(a.z,b.z), fminf(a.w,b.w)};
}
__device__ __forceinline__ float4 f4max(float4 a, float4 b) {
    return float4{fmaxf(a.x,b.x), fmaxf(a.y,b.y), fmaxf(a.z,b.z), fmaxf(a.w,b.w)};
}
__device__ __forceinline__ float4 f4add(float4 a, float s) {
    return float4{a.x+s, a.y+s, a.z+s, a.w+s};
}

// DPP cross-lane shifts: whole-wave 1-lane shift, boundary lane gets `edge`
// (old operand, bound_ctrl=false => out-of-range lanes keep old value).
// wave_shr:1 = 0x138 : lane i <- lane i-1  (shfl_up analog),  lane 0  <- edge
// wave_shl:1 = 0x130 : lane i <- lane i+1  (shfl_down analog), lane 63 <- edge
__device__ __forceinline__ float dpp_up1(float src, float edge) {
    return __int_as_float(__builtin_amdgcn_update_dpp(
        __float_as_int(edge), __float_as_int(src), 0x138, 0xf, 0xf, false));
}
__device__ __forceinline__ float dpp_dn1(float src, float edge) {
    return __int_as_float(__builtin_amdgcn_update_dpp(
        __float_as_int(edge), __float_as_int(src), 0x130, 0xf, 0xf, false));
}

// horizontal pass: window cols c-3..c+3; neighbors via DPP, edges injected
template<bool IS_MIN>
__device__ __forceinline__ float4 hpass(float4 v, float w1, float w2, float w3) {
    const float EDGE = IS_MIN ? __builtin_inff() : -__builtin_inff();
    const float ly = dpp_up1(v.y, EDGE);   // col 4l-3
    const float lz = dpp_up1(v.z, EDGE);   // col 4l-2
    const float lw = dpp_up1(v.w, EDGE);   // col 4l-1
    const float rx = dpp_dn1(v.x, EDGE);   // col 4l+4
    const float ry = dpp_dn1(v.y, EDGE);   // col 4l+5
    const float rz = dpp_dn1(v.z, EDGE);   // col 4l+6
    const float win[10] = {ly, lz, lw, v.x, v.y, v.z, v.w, rx, ry, rz};
    float o[4];
#pragma unroll
    for (int m = 0; m < 4; ++m) {
        const float v0 = win[m+3];
        if (IS_MIN) {
            const float m1 = fminf(win[m+2], win[m+4]) + w1;
            const float m2 = fminf(win[m+1], win[m+5]) + w2;
            const float m3 = fminf(win[m],   win[m+6]) + w3;
            o[m] = fminf(fminf(fminf(v0, m1), m2), m3);   // chain -> v_min3
        } else {
            const float m1 = fmaxf(win[m+2], win[m+4]) - w1;
            const float m2 = fmaxf(win[m+1], win[m+5]) - w2;
            const float m3 = fmaxf(win[m],   win[m+6]) - w3;
            o[m] = fmaxf(fmaxf(fmaxf(v0, m1), m2), m3);   // chain -> v_max3
        }
    }
    return float4{o[0], o[1], o[2], o[3]};
}

// vertical pass over a 7-row register window (w[3] = center row)
template<bool IS_MIN>
__device__ __forceinline__ float4 vpass(const float4 w[7], float w1, float w2,
                                        float w3) {
    if (IS_MIN) {
        const float4 m1 = f4add(f4min(w[2], w[4]),  w1);
        const float4 m2 = f4add(f4min(w[1], w[5]),  w2);
        const float4 m3 = f4add(f4min(w[0], w[6]),  w3);
        return f4min(f4min(f4min(w[3], m1), m2), m3);
    } else {
        const float4 m1 = f4add(f4max(w[2], w[4]), -w1);
        const float4 m2 = f4add(f4max(w[1], w[5]), -w2);
        const float4 m3 = f4add(f4max(w[0], w[6]), -w3);
        return f4max(f4max(f4max(w[3], m1), m2), m3);
    }
}

__device__ __forceinline__ float4 loadrow(const float* __restrict__ xp, int gr,
                                          int lane) {
    if ((unsigned)gr < (unsigned)HH)
        return *(const float4*)&xp[gr * WW + lane * 4];
    return f4s(__builtin_inff());          // erosion identity outside image
}

__global__ __launch_bounds__(NTH, 4) void parapool_stream(
    const float* __restrict__ x,
    const float* __restrict__ scale_min,
    const float* __restrict__ scale_max,
    float* __restrict__ out, int C)
{
    const int lane = threadIdx.x & 63;
    const int wv   = threadIdx.x >> 6;
    const int gid  = blockIdx.x * 4 + wv;     // strip id; block = 4 adjacent strips
    const int sPerImg = HH / ROWS;            // 16
    const int bc = gid / sPerImg;
    const int st = gid - bc * sPerImg;
    const int ch = bc % C;
    const int rs = st * ROWS;

    const float sn = scale_min[ch];
    const float sx = scale_max[ch];
    const float w1n = 1.0f*sn, w2n = 4.0f*sn, w3n = 9.0f*sn;
    const float w1x = 1.0f*sx, w2x = 4.0f*sx, w3x = 9.0f*sx;

    const float* __restrict__ xp = x   + (size_t)bc * (HH * WW);
    float* __restrict__       op = out + (size_t)bc * (HH * WW);

    const float INF = __builtin_inff();
    float4 hw[7], mw[7];                      // Hmin / Hmax rolling windows
#pragma unroll
    for (int k = 0; k < 7; ++k) { hw[k] = f4s(INF); mw[k] = f4s(-INF); }

    // prefetch depth 2: row gr's data is requested 2 iterations before use
    float4 xn0 = loadrow(xp, rs - 6, lane);
    float4 xn1 = loadrow(xp, rs - 5, lane);

#pragma unroll 2
    for (int it = 0; it < ROWS + 12; ++it) {
        const int gr = rs - 6 + it;           // current X row
        const float4 xv = xn0;
        xn0 = xn1;
        xn1 = loadrow(xp, gr + 2, lane);

        // H-erosion of row gr -> push into hw
        const float4 hm = hpass<true>(xv, w1n, w2n, w3n);
#pragma unroll
        for (int k = 0; k < 6; ++k) hw[k] = hw[k+1];
        hw[6] = hm;

        if (it >= 6) {                        // wave-uniform guard: dead before
            // V-erosion -> E row er (-inf outside image), then H-dilation
            const int er = gr - 3;
            float4 E;
            if ((unsigned)er < (unsigned)HH)
                E = vpass<true>(hw, w1n, w2n, w3n);
            else
                E = f4s(-INF);
            const float4 hx = hpass<false>(E, w1x, w2x, w3x);
#pragma unroll
            for (int k = 0; k < 6; ++k) mw[k] = mw[k+1];
            mw[6] = hx;

            // V-dilation -> out row gr-6 (valid once both windows are warm)
            if (it >= 12) {
                const float4 o = vpass<false>(mw, w1x, w2x, w3x);
                *(float4*)&op[(gr - 6) * WW + lane * 4] = o;
            }
        }
    }
}

extern "C" void kernel_launch(void* const* d_in, const int* in_sizes, int n_in,
                              void* d_out, int out_size, void* d_ws, size_t ws_size,
                              hipStream_t stream) {
    const float* x    = (const float*)d_in[0];
    const float* smin = (const float*)d_in[1];
    const float* smax = (const float*)d_in[2];
    float* out = (float*)d_out;

    const int C = in_sizes[1];                    // 64
    const int B = in_sizes[0] / (C * HH * WW);    // 8

    const int totalStrips = B * C * (HH / ROWS);  // 8192
    dim3 grid(totalStrips / 4);                   // 2048 blocks x 4 waves
    parapool_stream<<<grid, NTH, 0, stream>>>(x, smin, smax, out, C);
}

// Round 9
// 246.136 us; speedup vs baseline: 1.0382x; 1.0382x over previous
//
#include <hip/hip_runtime.h>

// Parabolic morphological pooling: min-plus erosion then max-plus dilation,
// 7x7 parabola ||z||^2 * scale_c, 'same' padding. Register-streaming design.
//
// Round-9 = round-6 (full unroll, ROWS=32) + round-8 (DPP lane shifts):
//   - Full unroll of the 44-iter pipeline: window shifts become register
//     renaming (zero v_mov), warm-up guards constant-fold.
//   - Horizontal neighbor exchange via DPP wave_shr:1/wave_shl:1
//     (pure VALU, ~no latency, boundary +-inf injected via `old` operand) —
//     no DS instructions at all, removing r6's ds_bpermute serial chain.
//   - ROWS=32: warm-up multiplier 1.375x (vs 1.75x at ROWS=16).
//
//   - One wave owns a 256-wide row: lane l holds cols 4l..4l+3 (float4).
//   - Vertical passes: per-lane rolling 7-row register windows.
//   - Pipeline: X[gr] -> Hmin[gr] -> E[gr-3] -> Hmax[gr-3] -> out[gr-6].
//   - Outside image: +inf (erosion input), -inf (erosion output / dilation).
// Expression tree identical to rounds 2/4/6/7/8 (all absmax 0.0).

#define ROWS 32
#define HH   256
#define WW   256
#define NTH  256

__device__ __forceinline__ float4 f4s(float v) { return float4{v, v, v, v}; }

__device__ __forceinline__ float4 f4min(float4 a, float4 b) {
    return float4{fminf(a.x,b.x), fminf(a.y,b.y), fminf(a.z,b.z), fminf(a.w,b.w)};
}
__device__ __forceinline__ float4 f4max(float4 a, float4 b) {
    return float4{fmaxf(a.x,b.x), fmaxf(a.y,b.y), fmaxf(a.z,b.z), fmaxf(a.w,b.w)};
}
__device__ __forceinline__ float4 f4add(float4 a, float s) {
    return float4{a.x+s, a.y+s, a.z+s, a.w+s};
}

// DPP cross-lane shifts: whole-wave 1-lane shift, boundary lane gets `edge`
// (old operand; bound_ctrl=false => out-of-range lanes keep old value).
// wave_shr:1 = 0x138 : lane i <- lane i-1 (shfl_up analog),  lane 0  <- edge
// wave_shl:1 = 0x130 : lane i <- lane i+1 (shfl_down analog), lane 63 <- edge
__device__ __forceinline__ float dpp_up1(float src, float edge) {
    return __int_as_float(__builtin_amdgcn_update_dpp(
        __float_as_int(edge), __float_as_int(src), 0x138, 0xf, 0xf, false));
}
__device__ __forceinline__ float dpp_dn1(float src, float edge) {
    return __int_as_float(__builtin_amdgcn_update_dpp(
        __float_as_int(edge), __float_as_int(src), 0x130, 0xf, 0xf, false));
}

// horizontal pass: window cols c-3..c+3; neighbors via DPP, edges injected
template<bool IS_MIN>
__device__ __forceinline__ float4 hpass(float4 v, float w1, float w2, float w3) {
    const float EDGE = IS_MIN ? __builtin_inff() : -__builtin_inff();
    const float ly = dpp_up1(v.y, EDGE);   // col 4l-3
    const float lz = dpp_up1(v.z, EDGE);   // col 4l-2
    const float lw = dpp_up1(v.w, EDGE);   // col 4l-1
    const float rx = dpp_dn1(v.x, EDGE);   // col 4l+4
    const float ry = dpp_dn1(v.y, EDGE);   // col 4l+5
    const float rz = dpp_dn1(v.z, EDGE);   // col 4l+6
    const float win[10] = {ly, lz, lw, v.x, v.y, v.z, v.w, rx, ry, rz};
    float o[4];
#pragma unroll
    for (int m = 0; m < 4; ++m) {
        const float v0 = win[m+3];
        if (IS_MIN) {
            const float m1 = fminf(win[m+2], win[m+4]) + w1;
            const float m2 = fminf(win[m+1], win[m+5]) + w2;
            const float m3 = fminf(win[m],   win[m+6]) + w3;
            o[m] = fminf(fminf(fminf(v0, m1), m2), m3);   // chain -> v_min3
        } else {
            const float m1 = fmaxf(win[m+2], win[m+4]) - w1;
            const float m2 = fmaxf(win[m+1], win[m+5]) - w2;
            const float m3 = fmaxf(win[m],   win[m+6]) - w3;
            o[m] = fmaxf(fmaxf(fmaxf(v0, m1), m2), m3);   // chain -> v_max3
        }
    }
    return float4{o[0], o[1], o[2], o[3]};
}

// vertical pass over a 7-row register window (w[3] = center row)
template<bool IS_MIN>
__device__ __forceinline__ float4 vpass(const float4 w[7], float w1, float w2,
                                        float w3) {
    if (IS_MIN) {
        const float4 m1 = f4add(f4min(w[2], w[4]),  w1);
        const float4 m2 = f4add(f4min(w[1], w[5]),  w2);
        const float4 m3 = f4add(f4min(w[0], w[6]),  w3);
        return f4min(f4min(f4min(w[3], m1), m2), m3);
    } else {
        const float4 m1 = f4add(f4max(w[2], w[4]), -w1);
        const float4 m2 = f4add(f4max(w[1], w[5]), -w2);
        const float4 m3 = f4add(f4max(w[0], w[6]), -w3);
        return f4max(f4max(f4max(w[3], m1), m2), m3);
    }
}

__device__ __forceinline__ float4 loadrow(const float* __restrict__ xp, int gr,
                                          int lane) {
    if ((unsigned)gr < (unsigned)HH)
        return *(const float4*)&xp[gr * WW + lane * 4];
    return f4s(__builtin_inff());          // erosion identity outside image
}

__global__ __launch_bounds__(NTH, 4) void parapool_stream(
    const float* __restrict__ x,
    const float* __restrict__ scale_min,
    const float* __restrict__ scale_max,
    float* __restrict__ out, int C)
{
    const int lane = threadIdx.x & 63;
    const int wv   = threadIdx.x >> 6;
    const int gid  = blockIdx.x * 4 + wv;     // strip id; block = 4 adjacent strips
    const int sPerImg = HH / ROWS;            // 8
    const int bc = gid / sPerImg;
    const int st = gid - bc * sPerImg;
    const int ch = bc % C;
    const int rs = st * ROWS;

    const float sn = scale_min[ch];
    const float sx = scale_max[ch];
    const float w1n = 1.0f*sn, w2n = 4.0f*sn, w3n = 9.0f*sn;
    const float w1x = 1.0f*sx, w2x = 4.0f*sx, w3x = 9.0f*sx;

    const float* __restrict__ xp = x   + (size_t)bc * (HH * WW);
    float* __restrict__       op = out + (size_t)bc * (HH * WW);

    const float INF = __builtin_inff();
    float4 hw[7], mw[7];                      // Hmin / Hmax rolling windows
#pragma unroll
    for (int k = 0; k < 7; ++k) { hw[k] = f4s(INF); mw[k] = f4s(-INF); }

    // prefetch depth 2: row gr's data is requested 2 iterations before use
    float4 xn0 = loadrow(xp, rs - 6, lane);
    float4 xn1 = loadrow(xp, rs - 5, lane);

    // Fully-unrolled 6-row-deep pipeline: window shifts become register
    // renames; it<6 / it<12 guards constant-fold to skipped code.
#pragma unroll
    for (int it = 0; it < ROWS + 12; ++it) {
        const int gr = rs - 6 + it;           // current X row
        const float4 xv = xn0;
        xn0 = xn1;
        xn1 = loadrow(xp, gr + 2, lane);

        // H-erosion of row gr -> push into hw
        const float4 hm = hpass<true>(xv, w1n, w2n, w3n);
#pragma unroll
        for (int k = 0; k < 6; ++k) hw[k] = hw[k+1];
        hw[6] = hm;

        if (it >= 6) {                        // statically dead before it=6
            // V-erosion -> E row er (-inf outside image), then H-dilation
            const int er = gr - 3;
            float4 E;
            if ((unsigned)er < (unsigned)HH)
                E = vpass<true>(hw, w1n, w2n, w3n);
            else
                E = f4s(-INF);
            const float4 hx = hpass<false>(E, w1x, w2x, w3x);
#pragma unroll
            for (int k = 0; k < 6; ++k) mw[k] = mw[k+1];
            mw[6] = hx;

            // V-dilation -> out row gr-6 (valid once both windows are warm)
            if (it >= 12) {
                const float4 o = vpass<false>(mw, w1x, w2x, w3x);
                *(float4*)&op[(gr - 6) * WW + lane * 4] = o;
            }
        }
    }
}

extern "C" void kernel_launch(void* const* d_in, const int* in_sizes, int n_in,
                              void* d_out, int out_size, void* d_ws, size_t ws_size,
                              hipStream_t stream) {
    const float* x    = (const float*)d_in[0];
    const float* smin = (const float*)d_in[1];
    const float* smax = (const float*)d_in[2];
    float* out = (float*)d_out;

    const int C = in_sizes[1];                    // 64
    const int B = in_sizes[0] / (C * HH * WW);    // 8

    const int totalStrips = B * C * (HH / ROWS);  // 4096
    dim3 grid(totalStrips / 4);                   // 1024 blocks x 4 waves
    parapool_stream<<<grid, NTH, 0, stream>>>(x, smin, smax, out, C);
}